// Round 5
// baseline (239.728 us; speedup 1.0000x reference)
//
#include <hip/hip_runtime.h>

#define D_DIM 512

typedef float f32x2 __attribute__((ext_vector_type(2)));

__device__ __forceinline__ float flog2(float x) {
    return __builtin_amdgcn_logf(x);   // v_log_f32 (= log2); inputs >= ~4e-6, no denormal wrapper
}

// ============ per-row sums: E[row] = sum_d x*log2(x). One wave/row, 4 rows/block ============
__global__ __launch_bounds__(256)
void jsd_entropy_kernel(const float* __restrict__ a,
                        const float* __restrict__ b,
                        float* __restrict__ E, int N, int M) {
    const int wave = threadIdx.x >> 6;
    const int lane = threadIdx.x & 63;
    const int row = blockIdx.x * 4 + wave;
    if (row >= N + M) return;
    const float* src = (row < N) ? (a + (size_t)row * D_DIM)
                                 : (b + (size_t)(row - N) * D_DIM);
    const float4* s4 = (const float4*)src;
    float4 v0 = s4[lane];
    float4 v1 = s4[lane + 64];
    float s = 0.f;
    s = fmaf(v0.x, flog2(v0.x), s);
    s = fmaf(v0.y, flog2(v0.y), s);
    s = fmaf(v0.z, flog2(v0.z), s);
    s = fmaf(v0.w, flog2(v0.w), s);
    s = fmaf(v1.x, flog2(v1.x), s);
    s = fmaf(v1.y, flog2(v1.y), s);
    s = fmaf(v1.z, flog2(v1.z), s);
    s = fmaf(v1.w, flog2(v1.w), s);
#pragma unroll
    for (int off = 32; off > 0; off >>= 1) s += __shfl_down(s, off, 64);
    if (lane == 0) E[row] = s;
}

// ============ main ============
// out[i,j] = 1 + 0.5*(Ea[i]+Eb[j]) - 0.5*sum_d t*log2(t), t = a_i[d]+b_j[d]
//
// Block = 4 waves = one 32x32 tile x 4 INDEPENDENT d-quarters; no barrier in the
// main loop. Wave-private 4 KB LDS, double-buffered global_load_lds, own vmcnt.
// 16 KB LDS/block + VGPR<=64 -> 8 blocks/CU = 8 independent waves/SIMD.
//
// Staging uses a PERMUTED lane->(row,slot) mapping instead of an XOR swizzle:
//   lane l fetches (row 4*(l&7)+(l>>4), 16B-slot (l>>3)&1)
// so the compute-side b128 read of (row 4*g+i, slot q) sits at byte offset
//   (i*2+q)*128 + g*16   (g = lr for A, lc for B)
// i.e. ONE base register + compile-time immediates, and the 8 g-groups cover
// 8 distinct 4-bank ranges -> conflict-free broadcast reads, zero per-q VALU.
constexpr int DK  = 8;           // d per chunk
constexpr int QD  = 128;         // d per wave (quarter)
constexpr int NCH = QD / DK;     // 16

__device__ __forceinline__ void stage1(const float* gp, float* lbuf) {
    __builtin_amdgcn_global_load_lds(
        (const __attribute__((address_space(1))) void*)gp,
        (__attribute__((address_space(3))) void*)lbuf,
        16, 0, 0);
}

__device__ __forceinline__ void computeChunk(const float* __restrict__ Ab,
                                             const float* __restrict__ Bb,
                                             f32x2 acc2[4][4]) {
#pragma unroll
    for (int q = 0; q < 2; ++q) {
        float4 av[4], bv[4];
#pragma unroll
        for (int i = 0; i < 4; ++i) {
            av[i] = *(const float4*)(Ab + (i * 2 + q) * 32);
            bv[i] = *(const float4*)(Bb + (i * 2 + q) * 32);
        }
#pragma unroll
        for (int rr = 0; rr < 4; ++rr) {
            const f32x2 a0 = {av[rr].x, av[rr].y};
            const f32x2 a1 = {av[rr].z, av[rr].w};
#pragma unroll
            for (int cc = 0; cc < 4; ++cc) {
                f32x2 t0 = a0 + (f32x2){bv[cc].x, bv[cc].y};   // v_pk_add_f32
                f32x2 t1 = a1 + (f32x2){bv[cc].z, bv[cc].w};
                f32x2 l0 = {flog2(t0.x), flog2(t0.y)};
                f32x2 l1 = {flog2(t1.x), flog2(t1.y)};
                acc2[rr][cc] = __builtin_elementwise_fma(t0, l0, acc2[rr][cc]);  // v_pk_fma_f32
                acc2[rr][cc] = __builtin_elementwise_fma(t1, l1, acc2[rr][cc]);
            }
        }
    }
}

__global__ __launch_bounds__(256, 8)
void jsd_main_kernel(const float* __restrict__ a, const float* __restrict__ b,
                     const float* __restrict__ Ea, const float* __restrict__ Eb,
                     float* __restrict__ out, int N, int M) {
    // [wave][seg][256 floats]; seg: 0=A/buf0 1=B/buf0 2=A/buf1 3=B/buf1  (16 KB)
    __shared__ __align__(16) float lds[4][4][256];

    const int tid = threadIdx.x;
    const int w   = tid >> 6;        // wave = d-quarter
    const int l   = tid & 63;
    const int lr  = l >> 3;          // lane row group: rows 4*lr..4*lr+3
    const int lc  = l & 7;           // lane col group: cols 4*lc..4*lc+3
    const int rowBase = blockIdx.y * 32;
    const int colBase = blockIdx.x * 32;

    // per-lane global source for the permuted staging
    const int pr = 4 * (l & 7) + (l >> 4);   // row this lane stages
    const int ps = (l >> 3) & 1;             // 16B slot this lane stages
    const float* gA = a + (size_t)(rowBase + pr) * D_DIM + w * QD + ps * 4;
    const float* gB = b + (size_t)(colBase + pr) * D_DIM + w * QD + ps * 4;

    float* A0 = &lds[w][0][0];
    float* B0 = &lds[w][1][0];
    float* A1 = &lds[w][2][0];
    float* B1 = &lds[w][3][0];
    const float* Ab0 = A0 + lr * 4;   // compute-side bases (all reads at imm offsets)
    const float* Bb0 = B0 + lc * 4;
    const float* Ab1 = A1 + lr * 4;
    const float* Bb1 = B1 + lc * 4;

    f32x2 acc2[4][4];
#pragma unroll
    for (int i = 0; i < 4; ++i)
#pragma unroll
        for (int j = 0; j < 4; ++j) acc2[i][j] = (f32x2){0.f, 0.f};

    stage1(gA, A0);
    stage1(gB, B0);

#pragma unroll 1
    for (int ck = 0; ck < NCH; ck += 2) {
        asm volatile("s_waitcnt vmcnt(0)" ::: "memory");   // chunk ck landed
        if (ck + 1 < NCH) {
            gA += DK; gB += DK;
            stage1(gA, A1); stage1(gB, B1);                // prefetch ck+1
        }
        __builtin_amdgcn_sched_barrier(0);
        computeChunk(Ab0, Bb0, acc2);

        asm volatile("s_waitcnt vmcnt(0)" ::: "memory");   // chunk ck+1 landed
        if (ck + 2 < NCH) {
            gA += DK; gB += DK;
            stage1(gA, A0); stage1(gB, B0);                // prefetch ck+2
        }
        __builtin_amdgcn_sched_barrier(0);
        computeChunk(Ab1, Bb1, acc2);
    }

    // -------- 4-way d-merge via LDS (two barriers, no atomics) --------
    float accs[16];
#pragma unroll
    for (int i = 0; i < 16; ++i) accs[i] = acc2[i >> 2][i & 3].x + acc2[i >> 2][i & 3].y;

    __syncthreads();                      // everyone done reading their LDS slice
    float* scratch = &lds[0][0][0];       // 4096 floats = exactly 16 KB
#pragma unroll
    for (int i = 0; i < 16; ++i)
        scratch[(w * 16 + i) * 64 + l] = accs[i];   // banks = l%32: 2-way (free)
    __syncthreads();

    // wave w combines + stores output rows 4*lr + w
    const int rr = w;
    float s[4];
#pragma unroll
    for (int cc = 0; cc < 4; ++cc) {
        float v = scratch[(0 * 16 + rr * 4 + cc) * 64 + l];
        v += scratch[(1 * 16 + rr * 4 + cc) * 64 + l];
        v += scratch[(2 * 16 + rr * 4 + cc) * 64 + l];
        v += scratch[(3 * 16 + rr * 4 + cc) * 64 + l];
        s[cc] = v;
    }
    const int row = rowBase + 4 * lr + rr;
    const float eav = Ea[row];
    const float4 eb = *(const float4*)&Eb[colBase + 4 * lc];
    const float base_v = 1.0f + 0.5f * eav;
    float4 v;
    v.x = fmaf(-0.5f, s[0], base_v + 0.5f * eb.x);
    v.y = fmaf(-0.5f, s[1], base_v + 0.5f * eb.y);
    v.z = fmaf(-0.5f, s[2], base_v + 0.5f * eb.z);
    v.w = fmaf(-0.5f, s[3], base_v + 0.5f * eb.w);
    *(float4*)(out + (size_t)row * M + colBase + 4 * lc) = v;
}

extern "C" void kernel_launch(void* const* d_in, const int* in_sizes, int n_in,
                              void* d_out, int out_size, void* d_ws, size_t ws_size,
                              hipStream_t stream) {
    const float* a = (const float*)d_in[0];
    const float* b = (const float*)d_in[1];
    const int N = in_sizes[0] / D_DIM;   // 1024
    const int M = in_sizes[1] / D_DIM;   // 1024
    float* E = (float*)d_ws;             // Ea[0..N), Eb[N..N+M)

    jsd_entropy_kernel<<<(N + M + 3) / 4, 256, 0, stream>>>(a, b, E, N, M);

    dim3 grid(M / 32, N / 32);           // 32 x 32 = 1024 blocks -> 8 blocks/CU target
    jsd_main_kernel<<<grid, 256, 0, stream>>>(a, b, E, E + N, (float*)d_out, N, M);
}

// Round 6
// 108.093 us; speedup vs baseline: 2.2178x; 2.2178x over previous
//
#include <hip/hip_runtime.h>

#define D_DIM 512

typedef float f32x2 __attribute__((ext_vector_type(2)));

__device__ __forceinline__ float flog2(float x) {
    return __builtin_amdgcn_logf(x);   // v_log_f32 (= log2); inputs >= ~4e-6, no denormal wrapper
}

// ============ per-row sums: E[row] = sum_d x*log2(x). One wave/row, 4 rows/block ============
__global__ __launch_bounds__(256)
void jsd_entropy_kernel(const float* __restrict__ a,
                        const float* __restrict__ b,
                        float* __restrict__ E, int N, int M) {
    const int wave = threadIdx.x >> 6;
    const int lane = threadIdx.x & 63;
    const int row = blockIdx.x * 4 + wave;
    if (row >= N + M) return;
    const float* src = (row < N) ? (a + (size_t)row * D_DIM)
                                 : (b + (size_t)(row - N) * D_DIM);
    const float4* s4 = (const float4*)src;
    float4 v0 = s4[lane];
    float4 v1 = s4[lane + 64];
    float s = 0.f;
    s = fmaf(v0.x, flog2(v0.x), s);
    s = fmaf(v0.y, flog2(v0.y), s);
    s = fmaf(v0.z, flog2(v0.z), s);
    s = fmaf(v0.w, flog2(v0.w), s);
    s = fmaf(v1.x, flog2(v1.x), s);
    s = fmaf(v1.y, flog2(v1.y), s);
    s = fmaf(v1.z, flog2(v1.z), s);
    s = fmaf(v1.w, flog2(v1.w), s);
#pragma unroll
    for (int off = 32; off > 0; off >>= 1) s += __shfl_down(s, off, 64);
    if (lane == 0) E[row] = s;
}

// ============ main ============
// out[i,j] = 1 + 0.5*(Ea[i]+Eb[j]) - 0.5*sum_d t*log2(t), t = a_i[d]+b_j[d]
//
// Round-4 structure (best: 60.5 us) + software-pipelined LDS reads.
// Block = 4 waves = one 32x32 tile x 4 INDEPENDENT d-quarters; no barrier in the
// main loop. Wave-private 8 KB LDS slice, double-buffered global_load_lds, own
// vmcnt. launch_bounds(256,4): VGPR cap 128 (body ~105, NO spill — the (256,8)
// 64-cap spilled acc to scratch: 845 MB HBM traffic, round 5).
// Per q-iter the 8 ds_read_b128 for q+1 are loaded into alternate registers
// while q computes -> ds latency hidden, was ~8-10 us of no-issue idle.
constexpr int DK  = 16;          // d per chunk (row = 64 B in LDS, 4 float4 slots)
constexpr int QD  = 128;         // d per wave (quarter)
constexpr int NCH = QD / DK;     // 8

// Stage 32 rows x 16 d into linear LDS [32][16] (wave-private).
// Swizzle: LDS[r][16B-slot s] = global[r][slot s ^ ((r>>2)&3)], applied by
// pre-swizzling the per-lane GLOBAL source (LDS dest must stay linear).
__device__ __forceinline__ void stageW(const float* __restrict__ g, float* lbuf, int l) {
#pragma unroll
    for (int k = 0; k < 2; ++k) {
        const int r0 = 16 * k;
        const int r  = r0 + (l >> 2);
        const int c  = (l & 3) ^ ((r >> 2) & 3);
        const float* gp = g + (size_t)r * D_DIM + 4 * c;
        __builtin_amdgcn_global_load_lds(
            (const __attribute__((address_space(1))) void*)gp,
            (__attribute__((address_space(3))) void*)(lbuf + r0 * DK),
            16, 0, 0);
    }
}

__global__ __launch_bounds__(256, 4)
void jsd_main_kernel(const float* __restrict__ a, const float* __restrict__ b,
                     const float* __restrict__ Ea, const float* __restrict__ Eb,
                     float* __restrict__ out, int N, int M) {
    __shared__ __align__(16) float lds[4][2][2][32][DK];   // [wave][buf][A/B][row][d] = 32 KB

    const int tid = threadIdx.x;
    const int w   = tid >> 6;        // wave = d-quarter
    const int l   = tid & 63;
    const int lr  = l >> 3;          // lane row group: rows 4*lr..4*lr+3
    const int lc  = l & 7;           // lane col group: cols 4*lc..4*lc+3
    const int rowBase = blockIdx.y * 32;
    const int colBase = blockIdx.x * 32;

    const float* aT = a + (size_t)rowBase * D_DIM + w * QD;
    const float* bT = b + (size_t)colBase * D_DIM + w * QD;

    float* A0 = &lds[w][0][0][0][0];
    float* B0 = &lds[w][0][1][0][0];
    float* A1 = &lds[w][1][0][0][0];
    float* B1 = &lds[w][1][1][0][0];

    f32x2 acc2[4][4];
#pragma unroll
    for (int i = 0; i < 4; ++i)
#pragma unroll
        for (int j = 0; j < 4; ++j) acc2[i][j] = (f32x2){0.f, 0.f};

    stageW(aT, A0, l);
    stageW(bT, B0, l);

    // q-slice LDS read: compile-time q, alternate register sets
#define LOADQ(qc, AV, BV)                                                      \
    do {                                                                       \
        const int sa_ = (((qc) ^ lr) & 3) << 2;                                \
        const int sb_ = (((qc) ^ lc) & 3) << 2;                                \
        _Pragma("unroll") for (int i_ = 0; i_ < 4; ++i_) {                     \
            AV[i_] = *(const float4*)&Aw[(4 * lr + i_) * DK + sa_];            \
            BV[i_] = *(const float4*)&Bw[(4 * lc + i_) * DK + sb_];            \
        }                                                                      \
    } while (0)

#define COMPQ(AV, BV)                                                          \
    do {                                                                       \
        _Pragma("unroll") for (int rr_ = 0; rr_ < 4; ++rr_) {                  \
            const f32x2 a0_ = {AV[rr_].x, AV[rr_].y};                          \
            const f32x2 a1_ = {AV[rr_].z, AV[rr_].w};                          \
            _Pragma("unroll") for (int cc_ = 0; cc_ < 4; ++cc_) {              \
                f32x2 t0_ = a0_ + (f32x2){BV[cc_].x, BV[cc_].y};               \
                f32x2 t1_ = a1_ + (f32x2){BV[cc_].z, BV[cc_].w};               \
                f32x2 l0_ = {flog2(t0_.x), flog2(t0_.y)};                      \
                f32x2 l1_ = {flog2(t1_.x), flog2(t1_.y)};                      \
                acc2[rr_][cc_] = __builtin_elementwise_fma(t0_, l0_, acc2[rr_][cc_]); \
                acc2[rr_][cc_] = __builtin_elementwise_fma(t1_, l1_, acc2[rr_][cc_]); \
            }                                                                  \
        }                                                                      \
    } while (0)

#pragma unroll 1
    for (int ck = 0; ck < NCH; ++ck) {
        asm volatile("s_waitcnt vmcnt(0)" ::: "memory");   // this wave's chunk landed
        const float* Aw = (ck & 1) ? A1 : A0;
        const float* Bw = (ck & 1) ? B1 : B0;
        if (ck + 1 < NCH) {            // prefetch next chunk; flies under this chunk's compute
            stageW(aT + (ck + 1) * DK, (ck & 1) ? A0 : A1, l);
            stageW(bT + (ck + 1) * DK, (ck & 1) ? B0 : B1, l);
        }
        __builtin_amdgcn_sched_barrier(0);   // keep load-issue ahead of compute

        // software-pipelined q loop: load q+1 while computing q
        float4 avA[4], bvA[4], avB[4], bvB[4];
        LOADQ(0, avA, bvA);
        LOADQ(1, avB, bvB);
        COMPQ(avA, bvA);
        LOADQ(2, avA, bvA);
        COMPQ(avB, bvB);
        LOADQ(3, avB, bvB);
        COMPQ(avA, bvA);
        COMPQ(avB, bvB);
    }
#undef LOADQ
#undef COMPQ

    // -------- 4-way d-merge via LDS (two barriers, no atomics) --------
    float accs[16];
#pragma unroll
    for (int i = 0; i < 16; ++i) accs[i] = acc2[i >> 2][i & 3].x + acc2[i >> 2][i & 3].y;

    __syncthreads();                       // everyone done reading their LDS slice
    float* scratch = &lds[0][0][0][0][0];  // 8192 floats; need 4*16*65 = 4160
#pragma unroll
    for (int i = 0; i < 16; ++i)
        scratch[(w * 16 + i) * 65 + l] = accs[i];   // stride 65: conflict-free
    __syncthreads();

    // wave w combines + stores output rows 4*lr + w
    const int rr = w;
    float s[4];
#pragma unroll
    for (int cc = 0; cc < 4; ++cc) {
        float v = scratch[(0 * 16 + rr * 4 + cc) * 65 + l];
        v += scratch[(1 * 16 + rr * 4 + cc) * 65 + l];
        v += scratch[(2 * 16 + rr * 4 + cc) * 65 + l];
        v += scratch[(3 * 16 + rr * 4 + cc) * 65 + l];
        s[cc] = v;
    }
    const int row = rowBase + 4 * lr + rr;
    const float eav = Ea[row];
    const float4 eb = *(const float4*)&Eb[colBase + 4 * lc];
    const float base_v = 1.0f + 0.5f * eav;
    float4 v;
    v.x = fmaf(-0.5f, s[0], base_v + 0.5f * eb.x);
    v.y = fmaf(-0.5f, s[1], base_v + 0.5f * eb.y);
    v.z = fmaf(-0.5f, s[2], base_v + 0.5f * eb.z);
    v.w = fmaf(-0.5f, s[3], base_v + 0.5f * eb.w);
    *(float4*)(out + (size_t)row * M + colBase + 4 * lc) = v;
}

extern "C" void kernel_launch(void* const* d_in, const int* in_sizes, int n_in,
                              void* d_out, int out_size, void* d_ws, size_t ws_size,
                              hipStream_t stream) {
    const float* a = (const float*)d_in[0];
    const float* b = (const float*)d_in[1];
    const int N = in_sizes[0] / D_DIM;   // 1024
    const int M = in_sizes[1] / D_DIM;   // 1024
    float* E = (float*)d_ws;             // Ea[0..N), Eb[N..N+M)

    jsd_entropy_kernel<<<(N + M + 3) / 4, 256, 0, stream>>>(a, b, E, N, M);

    dim3 grid(M / 32, N / 32);           // 32 x 32 = 1024 blocks -> 4 blocks/CU
    jsd_main_kernel<<<grid, 256, 0, stream>>>(a, b, E, E + N, (float*)d_out, N, M);
}